// Round 2
// baseline (364.097 us; speedup 1.0000x reference)
//
#include <hip/hip_runtime.h>
#include <hip/hip_bf16.h>

typedef __bf16 bf16;
typedef __bf16 bf16x4 __attribute__((ext_vector_type(4)));
typedef __bf16 bf16x8 __attribute__((ext_vector_type(8)));
typedef float  f32x4  __attribute__((ext_vector_type(4)));

static __device__ __forceinline__ f32x4 mfma16(bf16x8 a, bf16x8 b, f32x4 c) {
  return __builtin_amdgcn_mfma_f32_16x16x32_bf16(a, b, c, 0, 0, 0);
}

static __device__ __forceinline__ float fexp2(float x) {
  return __builtin_amdgcn_exp2f(x);  // raw v_exp_f32; args bounded ~[-30,30]
}

// Async global->LDS, 16B per lane; lane i lands at dst + i*16B (m97 pattern).
static __device__ __forceinline__ void gl_lds16(const bf16* g, bf16* l) {
  __builtin_amdgcn_global_load_lds(
      (const __attribute__((address_space(1))) void*)g,
      (__attribute__((address_space(3))) void*)l, 16, 0, 0);
}

// ---------------------------------------------------------------------------
// Fused weight transposes: 6 jobs in one launch.  out[z][c][r] = in[z][r][c].
// ---------------------------------------------------------------------------
struct TrTab {
  const float* src[6];
  bf16* dst[6];
  int R[6], C[6], ntx[6], nty[6];
  int base[7];
};

__global__ __launch_bounds__(256) void tr6_kernel(TrTab tab) {
  int bid = blockIdx.x;
  int j = 0;
  while (j < 5 && bid >= tab.base[j + 1]) ++j;
  const int local = bid - tab.base[j];
  const int R = tab.R[j], C = tab.C[j];
  const int ntx = tab.ntx[j];
  const int per_z = ntx * tab.nty[j];
  const int z = local / per_z;
  const int rem = local - z * per_z;
  const int by = rem / ntx, bx = rem - by * ntx;
  const float* in = tab.src[j];
  bf16* out = tab.dst[j];

  __shared__ bf16 tile[32][33];
  const size_t zoff = (size_t)z * R * C;
  const int tx = threadIdx.x & 31, ty = threadIdx.x >> 5;  // ty 0..7
  const int x = bx * 32 + tx;
  const int y0 = by * 32;
#pragma unroll
  for (int jj = 0; jj < 4; ++jj)
    tile[ty + jj * 8][tx] = (bf16)in[zoff + (size_t)(y0 + ty + jj * 8) * C + x];
  __syncthreads();
  const int x2 = y0 + tx;
  const int y2 = bx * 32;
#pragma unroll
  for (int jj = 0; jj < 4; ++jj)
    out[zoff + (size_t)(y2 + ty + jj * 8) * R + x2] = tile[tx][ty + jj * 8];
}

// bf16 batched transpose (for V -> V^T).
__global__ __launch_bounds__(256) void trb_kernel(const bf16* __restrict__ inp,
                                                  bf16* __restrict__ out,
                                                  int R, int C) {
  __shared__ bf16 tile[32][33];
  const size_t zoff = (size_t)blockIdx.z * R * C;
  const int tx = threadIdx.x & 31, ty = threadIdx.x >> 5;
  const int x = blockIdx.x * 32 + tx;
  const int y0 = blockIdx.y * 32;
#pragma unroll
  for (int j = 0; j < 4; ++j)
    tile[ty + j * 8][tx] = inp[zoff + (size_t)(y0 + ty + j * 8) * C + x];
  __syncthreads();
  const int x2 = y0 + tx;
  const int y2 = blockIdx.x * 32;
#pragma unroll
  for (int j = 0; j < 4; ++j)
    out[zoff + (size_t)(y2 + ty + j * 8) * R + x2] = tile[tx][ty + j * 8];
}

// ---------------------------------------------------------------------------
// LayerNorm over D=1024; one block per row; fp32 in, bf16 out.
// ---------------------------------------------------------------------------
__global__ __launch_bounds__(256) void ln_kernel(const float* __restrict__ inp,
                                                 const float* __restrict__ g,
                                                 const float* __restrict__ bt,
                                                 bf16* __restrict__ outp) {
  const int row = blockIdx.x;
  const int t = threadIdx.x;
  f32x4 v = ((const f32x4*)inp)[row * 256 + t];
  float s = v[0] + v[1] + v[2] + v[3];
  float sq = v[0] * v[0] + v[1] * v[1] + v[2] * v[2] + v[3] * v[3];
#pragma unroll
  for (int off = 32; off > 0; off >>= 1) {
    s += __shfl_xor(s, off);
    sq += __shfl_xor(sq, off);
  }
  __shared__ float red[8];
  const int wave = t >> 6, lane = t & 63;
  if (lane == 0) {
    red[wave] = s;
    red[wave + 4] = sq;
  }
  __syncthreads();
  s = red[0] + red[1] + red[2] + red[3];
  sq = red[4] + red[5] + red[6] + red[7];
  const float mu = s * (1.0f / 1024.0f);
  const float var = sq * (1.0f / 1024.0f) - mu * mu;
  const float rstd = rsqrtf(fmaxf(var, 0.0f) + 1e-5f);
  f32x4 gg = ((const f32x4*)g)[t];
  f32x4 bb = ((const f32x4*)bt)[t];
  bf16 o[4];
#pragma unroll
  for (int i = 0; i < 4; ++i)
    o[i] = (bf16)((v[i] - mu) * rstd * gg[i] + bb[i]);
  *(uint2*)&outp[(size_t)row * 1024 + 4 * t] = *(uint2*)o;
}

// ---------------------------------------------------------------------------
// GEMM epilogue selectors.
// ---------------------------------------------------------------------------
enum { EPI_QKV = 0, EPI_O = 1, EPI_FF1 = 2, EPI_FF2 = 3 };

// ---------------------------------------------------------------------------
// 256x256 8-phase GEMM (T2 swizzle + T3/T4 counted-vmcnt pipeline + T5).
// C = A @ Bt^T.  BK=64, 512 threads = 8 waves (2M x 4N), LDS 128 KB.
// Per K-tile: 4 phases, each {vmcnt(counted); barrier; ds_read frag subtile;
// issue 1 half-tile global_load_lds prefetch; lgkmcnt(0); setprio(1);
// 16 MFMA; setprio(0)}.  Stage order A0,B0,B1,A1 == consumption order, so
// steady-state waits are vmcnt(4) (never 0; 4-6 loads in flight across every
// barrier).  Buffer t&1 is overwritten one full K-tile after its last read,
// with a barrier in between (race-free by construction).
// ---------------------------------------------------------------------------
#define VMW(N) asm volatile("s_waitcnt vmcnt(" #N ")" ::: "memory")
#define BARR                        \
  do {                              \
    __builtin_amdgcn_s_barrier();   \
    asm volatile("" ::: "memory");  \
  } while (0)

template <int EPI>
__global__ __launch_bounds__(512) void gemm256(
    const bf16* __restrict__ A, const bf16* __restrict__ Bt, const int K,
    const float* __restrict__ bias, bf16* __restrict__ outB) {
  __shared__ __align__(16) bf16 sA[2][256 * 64];  // 64 KB
  __shared__ __align__(16) bf16 sB[2][256 * 64];  // 64 KB
  const int t = threadIdx.x;
  const int lane = t & 63, wave = t >> 6;
  const int quad = lane >> 4, l15 = lane & 15;
  const int wm = wave >> 2, wn = wave & 3;  // wave grid 2(M) x 4(N)
  const int m0 = blockIdx.y * 256, n0 = blockIdx.x * 256;
  const int srow = lane >> 3;
  const int scol = ((lane & 7) ^ srow) * 8;  // pre-swizzled global source
  const int bch = (wave & 3) + (wave >> 2) * 8;  // B-chunk id base

  // staging source pointers (advance by 64 elems per K-tile via ko)
  const bf16* aS0 = A + (size_t)(m0 + wave * 8 + srow) * K + scol;
  const bf16* aS1 = aS0 + (size_t)64 * K;
  const bf16* bS0 = Bt + (size_t)(n0 + bch * 8 + srow) * K + scol;
  const bf16* bS1 = bS0 + (size_t)32 * K;
  const size_t rsk = (size_t)128 * K;  // +16 chunks (128 rows)

  // half-tile stagers: 2 x global_load_lds each; chunk = 8 rows x 64 cols.
  // A-h0 = rows 0-63 & 128-191 (bit6==0); A-h1 = bit6==1.
  // B-h0 = rows with bit5==0 (chunks {0-3,8-11,16-19,24-27}); B-h1 = bit5==1.
  auto stA0 = [&](int buf, int ko) {
    gl_lds16(aS0 + ko, &sA[buf][wave * 512]);
    gl_lds16(aS0 + ko + rsk, &sA[buf][(wave + 16) * 512]);
  };
  auto stB0 = [&](int buf, int ko) {
    gl_lds16(bS0 + ko, &sB[buf][bch * 512]);
    gl_lds16(bS0 + ko + rsk, &sB[buf][(bch + 16) * 512]);
  };
  auto stB1 = [&](int buf, int ko) {
    gl_lds16(bS1 + ko, &sB[buf][(bch + 4) * 512]);
    gl_lds16(bS1 + ko + rsk, &sB[buf][(bch + 20) * 512]);
  };
  auto stA1 = [&](int buf, int ko) {
    gl_lds16(aS1 + ko, &sA[buf][(wave + 8) * 512]);
    gl_lds16(aS1 + ko + rsk, &sA[buf][(wave + 24) * 512]);
  };

  f32x4 acc[8][4];
#pragma unroll
  for (int i = 0; i < 8; ++i)
#pragma unroll
    for (int j = 0; j < 4; ++j) acc[i][j] = {0.f, 0.f, 0.f, 0.f};

  bf16x8 af[4][2], bf0[2][2], bf1[2][2];

  auto ldA = [&](int buf, int mh) {  // 8 x ds_read_b128
#pragma unroll
    for (int i = 0; i < 4; ++i) {
      const int row = wm * 128 + mh * 64 + i * 16 + l15;
#pragma unroll
      for (int ks = 0; ks < 2; ++ks) {
        const int col = ((ks * 4 + quad) ^ (row & 7)) * 8;
        af[i][ks] = *(const bf16x8*)&sA[buf][row * 64 + col];
      }
    }
  };
  auto ldB = [&](int buf, int nh, bf16x8 (&bfm)[2][2]) {  // 4 x ds_read_b128
#pragma unroll
    for (int j = 0; j < 2; ++j) {
      const int row = wn * 64 + nh * 32 + j * 16 + l15;
#pragma unroll
      for (int ks = 0; ks < 2; ++ks) {
        const int col = ((ks * 4 + quad) ^ (row & 7)) * 8;
        bfm[j][ks] = *(const bf16x8*)&sB[buf][row * 64 + col];
      }
    }
  };
  auto mm = [&](int mh, int nh, bf16x8 (&bfm)[2][2]) {  // 16 MFMA cluster
    asm volatile("s_waitcnt lgkmcnt(0)" ::: "memory");
    __builtin_amdgcn_sched_barrier(0);
    __builtin_amdgcn_s_setprio(1);
#pragma unroll
    for (int ks = 0; ks < 2; ++ks)
#pragma unroll
      for (int i = 0; i < 4; ++i)
#pragma unroll
        for (int j = 0; j < 2; ++j)
          acc[mh * 4 + i][nh * 2 + j] =
              mfma16(af[i][ks], bfm[j][ks], acc[mh * 4 + i][nh * 2 + j]);
    __builtin_amdgcn_s_setprio(0);
    __builtin_amdgcn_sched_barrier(0);
  };

  // prologue: stage T0 into buf0 in consumption order (A0,B0,B1,A1 = 8 loads)
  stA0(0, 0);
  stB0(0, 0);
  stB1(0, 0);
  stA1(0, 0);

  const int NT = K >> 6;
#pragma unroll 1
  for (int it = 0; it < NT - 1; ++it) {
    const int cur = it & 1, nxt = cur ^ 1;
    const int ko = (it + 1) * 64;
    // ph0: quadrant (mh0,nh0); needs T(it) A-h0+B-h0 (2 oldest half-tiles)
    VMW(4);
    BARR;
    ldA(cur, 0);
    ldB(cur, 0, bf0);
    stA0(nxt, ko);
    mm(0, 0, bf0);
    // ph1: (mh0,nh1); needs B-h1 (retire 3rd-oldest)
    VMW(4);
    BARR;
    ldB(cur, 1, bf1);
    stB0(nxt, ko);
    mm(0, 1, bf1);
    // ph2: (mh1,nh1); needs A-h1 (retire 4th-oldest)
    VMW(4);
    BARR;
    ldA(cur, 1);
    stB1(nxt, ko);
    mm(1, 1, bf1);
    // ph3: (mh1,nh0); no new LDS data guarantees needed -> no wait/barrier
    ldB(cur, 0, bf0);
    stA1(nxt, ko);
    mm(1, 0, bf0);
  }
  {  // last K-tile: no staging; drain 4 -> 2 -> 0
    const int cur = (NT - 1) & 1;
    VMW(4);
    BARR;
    ldA(cur, 0);
    ldB(cur, 0, bf0);
    mm(0, 0, bf0);
    VMW(2);
    BARR;
    ldB(cur, 1, bf1);
    mm(0, 1, bf1);
    VMW(0);
    BARR;
    ldA(cur, 1);
    mm(1, 1, bf1);
    ldB(cur, 0, bf0);
    mm(1, 0, bf0);
  }

  // C/D layout per 16x16 tile: row(m) = quad*4 + r, col(n) = l15.
#pragma unroll
  for (int ni = 0; ni < 4; ++ni) {
    const int n = n0 + wn * 64 + ni * 16 + l15;
    float bv = 0.f;
    if constexpr (EPI == EPI_FF1) bv = bias[n];
#pragma unroll
    for (int mi = 0; mi < 8; ++mi) {
#pragma unroll
      for (int r = 0; r < 4; ++r) {
        const int m = m0 + wm * 128 + mi * 16 + quad * 4 + r;
        float v = acc[mi][ni][r];
        if constexpr (EPI == EPI_QKV) {
          const int which = n >> 10, nn = n & 1023;
          const int h = nn >> 6, e = nn & 63;
          const int b = m >> 11, s2 = m & 2047;
          outB[(size_t)which * 4194304 +
               ((size_t)(b * 16 + h) * 2048 + s2) * 64 + e] = (bf16)v;
        } else {  // EPI_FF1
          v += bv;
          v = 0.5f * v * (1.0f + erff(v * 0.70710678118654752f));  // exact GELU
          outB[(size_t)m * 4096 + n] = (bf16)v;
        }
      }
    }
  }
}

// ---------------------------------------------------------------------------
// GEMM C = A @ Bt^T.  Tile 128 x 64, BK=64, 4 waves 2x2 (kept for the
// narrow-N epilogues: O-proj and FF2).  m99-style double buffer.
// ---------------------------------------------------------------------------
template <int EPI, bool NARROW>
__global__ __launch_bounds__(256) void gemm_bt(
    const bf16* __restrict__ A, const bf16* __restrict__ Bt, const int K,
    const float* __restrict__ bias, const float* __restrict__ res,
    bf16* __restrict__ outB, float* __restrict__ outF) {
  constexpr int BN = NARROW ? 64 : 128;
  constexpr int NI = NARROW ? 2 : 4;
  constexpr int BCH = BN / 32;  // B-chunks staged per wave
  __shared__ __align__(16) bf16 sA[2][128 * 64];
  __shared__ __align__(16) bf16 sB[2][BN * 64];
  const int t = threadIdx.x;
  const int lane = t & 63, wave = t >> 6;
  const int quad = lane >> 4, l15 = lane & 15;
  const int wr = wave >> 1, wc = wave & 1;
  const int m0 = blockIdx.y * 128, n0 = blockIdx.x * BN;
  const int srow = lane >> 3;
  const int scol = ((lane & 7) ^ srow) * 8;

  // per-thread staging pointers (advance by 64 elems per K-tile)
  const bf16* aPtr[4];
#pragma unroll
  for (int c = 0; c < 4; ++c)
    aPtr[c] = A + (size_t)(m0 + wave * 32 + c * 8 + srow) * K + scol;
  const bf16* bPtr[BCH];
#pragma unroll
  for (int c = 0; c < BCH; ++c)
    bPtr[c] = Bt + (size_t)(n0 + wave * (BCH * 8) + c * 8 + srow) * K + scol;

  f32x4 acc[4][NI];
#pragma unroll
  for (int i = 0; i < 4; ++i)
#pragma unroll
    for (int j = 0; j < NI; ++j) acc[i][j] = {0.f, 0.f, 0.f, 0.f};

  const int niter = K >> 6;
  // prologue: stage tile 0 into buffer 0
#pragma unroll
  for (int c = 0; c < 4; ++c)
    gl_lds16(aPtr[c], &sA[0][(wave * 4 + c) * 512]);
#pragma unroll
  for (int c = 0; c < BCH; ++c)
    gl_lds16(bPtr[c], &sB[0][(wave * BCH + c) * 512]);

  for (int it = 0; it < niter; ++it) {
    const int cur = it & 1, nxt = cur ^ 1;
    __syncthreads();  // drains cur-buf DMA; prior reads of nxt-buf complete
    if (it + 1 < niter) {
      const int off = (it + 1) * 64;
#pragma unroll
      for (int c = 0; c < 4; ++c)
        gl_lds16(aPtr[c] + off, &sA[nxt][(wave * 4 + c) * 512]);
#pragma unroll
      for (int c = 0; c < BCH; ++c)
        gl_lds16(bPtr[c] + off, &sB[nxt][(wave * BCH + c) * 512]);
    }
#pragma unroll
    for (int ks = 0; ks < 2; ++ks) {
      bf16x8 af[4], bfr[NI];
#pragma unroll
      for (int mi = 0; mi < 4; ++mi) {
        const int row = wr * 64 + mi * 16 + l15;
        const int col = ((ks * 4 + quad) ^ (row & 7)) * 8;
        af[mi] = *(const bf16x8*)&sA[cur][row * 64 + col];
      }
#pragma unroll
      for (int ni = 0; ni < NI; ++ni) {
        const int row = wc * (BN / 2) + ni * 16 + l15;
        const int col = ((ks * 4 + quad) ^ (row & 7)) * 8;
        bfr[ni] = *(const bf16x8*)&sB[cur][row * 64 + col];
      }
#pragma unroll
      for (int mi = 0; mi < 4; ++mi)
#pragma unroll
        for (int ni = 0; ni < NI; ++ni)
          acc[mi][ni] = mfma16(af[mi], bfr[ni], acc[mi][ni]);
    }
  }

  // C/D layout: within a 16x16 tile, row(m) = quad*4 + r, col(n) = l15.
#pragma unroll
  for (int mi = 0; mi < 4; ++mi) {
#pragma unroll
    for (int ni = 0; ni < NI; ++ni) {
      const int n = n0 + wc * (BN / 2) + ni * 16 + l15;
#pragma unroll
      for (int r = 0; r < 4; ++r) {
        const int m = m0 + wr * 64 + mi * 16 + quad * 4 + r;
        float v = acc[mi][ni][r];
        if constexpr (EPI == EPI_QKV) {
          const int which = n >> 10, nn = n & 1023;
          const int h = nn >> 6, e = nn & 63;
          const int b = m >> 11, s2 = m & 2047;
          outB[(size_t)which * 4194304 +
               ((size_t)(b * 16 + h) * 2048 + s2) * 64 + e] = (bf16)v;
        } else if constexpr (EPI == EPI_O) {
          v += bias[n] + res[(size_t)m * 1024 + n];
          outF[(size_t)m * 1024 + n] = v;  // fp32 hidden
        } else if constexpr (EPI == EPI_FF1) {
          v += bias[n];
          v = 0.5f * v * (1.0f + erff(v * 0.70710678118654752f));  // exact GELU
          outB[(size_t)m * 4096 + n] = (bf16)v;
        } else {  // EPI_FF2: hidden + ff -> fp32 OUTPUT
          v += bias[n] + res[(size_t)m * 1024 + n];
          outF[(size_t)m * 1024 + n] = v;
        }
      }
    }
  }
}

// ---------------------------------------------------------------------------
// Flash attention, non-causal, no max-shift (s/8 ~ N(0,1): exp2 safe).
// Block = 128 queries of one (b,h), 512 threads = 8 waves.
// Split-K: waves 0-3 do keys [0,1024), waves 4-7 keys [1024,2048); partials
// (o, l) merge via LDS at the end (no rescale needed -- no running max).
// ---------------------------------------------------------------------------
__global__ __launch_bounds__(512, 4) void attn_kernel(
    const bf16* __restrict__ q, const bf16* __restrict__ k,
    const bf16* __restrict__ vt, bf16* __restrict__ ao) {
  __shared__ __align__(16) bf16 sP[256 * 72];    // 36 KB: Q stage -> P -> merge
  __shared__ __align__(16) bf16 sK[2][64 * 64];  // 16 KB
  __shared__ __align__(16) bf16 sV[2][64 * 64];  // 16 KB  (V^T tiles [e][key])
  const int t = threadIdx.x;
  const int lane = t & 63, wave = t >> 6;  // wave 0..7
  const int wq = wave & 3, kh = wave >> 2;
  const int quad = lane >> 4, l15 = lane & 15;
  const int q0 = blockIdx.x * 128;
  const int bh = blockIdx.y, b = bh >> 4, h = bh & 15;
  const bf16* Q  = q  + (size_t)bh * 2048 * 64;
  const bf16* Kp = k  + (size_t)bh * 2048 * 64 + (size_t)kh * 1024 * 64;
  const bf16* Vt = vt + (size_t)bh * 64 * 2048 + kh * 1024;
  const int srow = lane >> 3;
  const int scol = ((lane & 7) ^ srow) * 8;
  const float SCL = 0.125f * 1.4426950408889634f;  // 1/8 * log2(e)

  // stage Q 128x64 into sP front at stride 64 (16 chunks of 8 rows)
#pragma unroll
  for (int c = 0; c < 2; ++c) {
    const int chunk = wave * 2 + c;  // 0..15
    const int row = chunk * 8 + srow;
    gl_lds16(&Q[(size_t)(q0 + row) * 64 + scol], &sP[chunk * 512]);
  }
  __syncthreads();
  bf16x8 qf[2][2];  // B-operand frags: queries wq*32 + mi*16 + l15
#pragma unroll
  for (int mi = 0; mi < 2; ++mi)
#pragma unroll
    for (int ks = 0; ks < 2; ++ks) {
      const int row = wq * 32 + mi * 16 + l15;
      const int col = ((ks * 4 + quad) ^ (row & 7)) * 8;
      qf[mi][ks] = *(const bf16x8*)&sP[row * 64 + col];
    }
  __syncthreads();  // qf loaded everywhere before P writes clobber sP

  f32x4 o[2][4];
  float ls[2] = {0.f, 0.f};
#pragma unroll
  for (int mi = 0; mi < 2; ++mi)
#pragma unroll
    for (int ne = 0; ne < 4; ++ne) o[mi][ne] = {0.f, 0.f, 0.f, 0.f};

  for (int kb = 0; kb < 16; ++kb) {
    const int kbase = kb * 64;
    __syncthreads();  // prior-iter sK/sV frag reads complete
#pragma unroll
    for (int c = 0; c < 2; ++c) {
      const int chunk = wq * 2 + c;  // 0..7 within this half's buffers
      const int row = chunk * 8 + srow;
      gl_lds16(&Kp[(size_t)(kbase + row) * 64 + scol], &sK[kh][chunk * 512]);
      gl_lds16(&Vt[(size_t)row * 2048 + kbase + scol], &sV[kh][chunk * 512]);
    }
    __syncthreads();

    // S^T = K Q^T : D[key = ni*16+quad*4+r][query = wq*32+mi*16+l15]
    f32x4 s[4][2];
#pragma unroll
    for (int ni = 0; ni < 4; ++ni)
#pragma unroll
      for (int mi = 0; mi < 2; ++mi) s[ni][mi] = {0.f, 0.f, 0.f, 0.f};
#pragma unroll
    for (int ks = 0; ks < 2; ++ks) {
      bf16x8 kf[4];
#pragma unroll
      for (int ni = 0; ni < 4; ++ni) {
        const int row = ni * 16 + l15;
        const int col = ((ks * 4 + quad) ^ (row & 7)) * 8;
        kf[ni] = *(const bf16x8*)&sK[kh][row * 64 + col];
      }
#pragma unroll
      for (int ni = 0; ni < 4; ++ni)
#pragma unroll
        for (int mi = 0; mi < 2; ++mi)
          s[ni][mi] = mfma16(kf[ni], qf[mi][ks], s[ni][mi]);
    }

    // p = exp2(s*SCL); 4 contiguous keys/reg -> b64 store; lane-partial sums
#pragma unroll
    for (int mi = 0; mi < 2; ++mi)
#pragma unroll
      for (int ni = 0; ni < 4; ++ni) {
        bf16x4 p4;
#pragma unroll
        for (int r = 0; r < 4; ++r) {
          const float p = fexp2(s[ni][mi][r] * SCL);
          ls[mi] += p;
          p4[r] = (bf16)p;
        }
        *(bf16x4*)&sP[(wave * 32 + mi * 16 + l15) * 72 + ni * 16 + quad * 4] =
            p4;
      }

    // O += P @ V  (sP rows are wave-private; no barrier needed)
#pragma unroll
    for (int ksb = 0; ksb < 2; ++ksb) {
      bf16x8 vf[4];
#pragma unroll
      for (int ne = 0; ne < 4; ++ne) {
        const int row = ne * 16 + l15;
        const int col = ((ksb * 4 + quad) ^ (row & 7)) * 8;
        vf[ne] = *(const bf16x8*)&sV[kh][row * 64 + col];
      }
#pragma unroll
      for (int mi = 0; mi < 2; ++mi) {
        const bf16x8 pf = *(const bf16x8*)&sP[(wave * 32 + mi * 16 + l15) * 72 +
                                              ksb * 32 + quad * 8];
#pragma unroll
        for (int ne = 0; ne < 4; ++ne)
          o[mi][ne] = mfma16(pf, vf[ne], o[mi][ne]);
      }
    }
  }

  // reduce lane-partial sums over quads: every lane gets its query's total
#pragma unroll
  for (int mi = 0; mi < 2; ++mi) {
    ls[mi] += __shfl_xor(ls[mi], 16);
    ls[mi] += __shfl_xor(ls[mi], 32);
  }

  // merge key halves: kh=1 publishes (o, l); kh=0 combines and writes out
  float* mo = (float*)sP;        // [4 wq][64 lane][32 floats]
  float* ml = (float*)sK;        // [4 wq][64 lane][2]
  __syncthreads();  // all PV reads of sP/sK done before scratch reuse
  if (kh == 1) {
    const int base = (wq * 64 + lane) * 32;
#pragma unroll
    for (int mi = 0; mi < 2; ++mi)
#pragma unroll
      for (int ne = 0; ne < 4; ++ne)
        *(f32x4*)&mo[base + (mi * 4 + ne) * 4] = o[mi][ne];
    ml[(wq * 64 + lane) * 2 + 0] = ls[0];
    ml[(wq * 64 + lane) * 2 + 1] = ls[1];
  }
  __syncthreads();
  if (kh == 0) {
    const int base = (wq * 64 + lane) * 32;
#pragma unroll
    for (int mi = 0; mi < 2; ++mi) {
#pragma unroll
      for (int ne = 0; ne < 4; ++ne) {
        const f32x4 add = *(const f32x4*)&mo[base + (mi * 4 + ne) * 4];
#pragma unroll
        for (int r = 0; r < 4; ++r) o[mi][ne][r] += add[r];
      }
      ls[mi] += ml[(wq * 64 + lane) * 2 + mi];
      ls[mi] = 1.0f / fmaxf(ls[mi], 1e-30f);
    }
#pragma unroll
    for (int mi = 0; mi < 2; ++mi) {
      float linv[4];
#pragma unroll
      for (int r = 0; r < 4; ++r) linv[r] = __shfl(ls[mi], quad * 4 + r);
#pragma unroll
      for (int ne = 0; ne < 4; ++ne)
#pragma unroll
        for (int r = 0; r < 4; ++r) {
          const int row = q0 + wq * 32 + mi * 16 + quad * 4 + r;
          const int col = h * 64 + ne * 16 + l15;
          ao[((size_t)(b * 2048 + row)) * 1024 + col] =
              (bf16)(o[mi][ne][r] * linv[r]);
        }
    }
  }
}

// ---------------------------------------------------------------------------
extern "C" void kernel_launch(void* const* d_in, const int* in_sizes, int n_in,
                              void* d_out, int out_size, void* d_ws,
                              size_t ws_size, hipStream_t stream) {
  const float* x    = (const float*)d_in[0];
  const float* Wq   = (const float*)d_in[1];
  const float* Wk   = (const float*)d_in[2];
  const float* Wv   = (const float*)d_in[3];
  const float* Wo   = (const float*)d_in[4];
  const float* bo   = (const float*)d_in[5];
  const float* ln1g = (const float*)d_in[6];
  const float* ln1b = (const float*)d_in[7];
  const float* ln2g = (const float*)d_in[8];
  const float* ln2b = (const float*)d_in[9];
  const float* W1   = (const float*)d_in[10];
  const float* b1   = (const float*)d_in[11];
  const float* W2   = (const float*)d_in[12];
  const float* b2   = (const float*)d_in[13];

  char* ws = (char*)d_ws;
  const size_t MB = 1ull << 20;
  bf16* QKVT = (bf16*)(ws);              // [3072][1024]: WqT,WkT,WvT stacked
  bf16* WqT  = QKVT;
  bf16* WkT  = (bf16*)(ws + 2 * MB);
  bf16* WvT  = (bf16*)(ws + 4 * MB);
  bf16* WoT  = (bf16*)(ws + 6 * MB);     // [1024][1024]
  bf16* W1T  = (bf16*)(ws + 8 * MB);     // [4096][1024]
  bf16* W2T  = (bf16*)(ws + 16 * MB);    // [1024][4096]
  bf16* sh8  = (bf16*)(ws + 24 * MB);    // shared slot: xn -> aoc -> hn
  bf16* qb   = (bf16*)(ws + 32 * MB);    // [b][h][s][e]
  bf16* kb   = (bf16*)(ws + 40 * MB);
  bf16* vb   = (bf16*)(ws + 48 * MB);
  bf16* vtb  = (bf16*)(ws + 56 * MB);    // [b][h][e][s]
  bf16* h1   = (bf16*)(ws + 32 * MB);    // [4096][4096] (after attn)
  float* hid = (float*)(ws + 64 * MB);   // fp32 hidden; peak 80 MB

  const dim3 blk(256);

  // fused weight transposes: 6 jobs, one launch
  TrTab tab;
  const float* srcs[6] = {Wq, Wk, Wv, Wo, W1, W2};
  bf16* dsts[6] = {WqT, WkT, WvT, WoT, W1T, W2T};
  const int Rs[6] = {1024, 1024, 1024, 1024, 1024, 4096};
  const int Cs[6] = {64, 64, 64, 1024, 4096, 1024};
  const int Zs[6] = {16, 16, 16, 1, 1, 1};
  int base = 0;
  for (int j = 0; j < 6; ++j) {
    tab.src[j] = srcs[j];
    tab.dst[j] = dsts[j];
    tab.R[j] = Rs[j];
    tab.C[j] = Cs[j];
    tab.ntx[j] = Cs[j] / 32;
    tab.nty[j] = Rs[j] / 32;
    tab.base[j] = base;
    base += (Cs[j] / 32) * (Rs[j] / 32) * Zs[j];
  }
  tab.base[6] = base;  // 12288
  tr6_kernel<<<base, blk, 0, stream>>>(tab);

  ln_kernel<<<4096, blk, 0, stream>>>(x, ln1g, ln1b, sh8);              // xn
  gemm256<EPI_QKV><<<dim3(12, 16), dim3(512), 0, stream>>>(
      sh8, QKVT, 1024, nullptr, qb);
  trb_kernel<<<dim3(2, 64, 32), blk, 0, stream>>>(vb, vtb, 2048, 64);
  attn_kernel<<<dim3(16, 32), dim3(512), 0, stream>>>(qb, kb, vtb, sh8);
  gemm_bt<EPI_O, true><<<dim3(16, 32), blk, 0, stream>>>(
      sh8, WoT, 1024, bo, x, nullptr, hid);
  ln_kernel<<<4096, blk, 0, stream>>>(hid, ln2g, ln2b, sh8);            // hn
  gemm256<EPI_FF1><<<dim3(16, 16), dim3(512), 0, stream>>>(
      sh8, W1T, 1024, b1, h1);
  gemm_bt<EPI_FF2, true><<<dim3(16, 32), blk, 0, stream>>>(
      h1, W2T, 4096, b2, hid, nullptr, (float*)d_out);

  (void)in_sizes; (void)n_in; (void)out_size; (void)ws_size;
}

// Round 3
// 357.256 us; speedup vs baseline: 1.0191x; 1.0191x over previous
//
#include <hip/hip_runtime.h>
#include <hip/hip_bf16.h>

typedef __bf16 bf16;
typedef __bf16 bf16x4 __attribute__((ext_vector_type(4)));
typedef __bf16 bf16x8 __attribute__((ext_vector_type(8)));
typedef float  f32x4  __attribute__((ext_vector_type(4)));

static __device__ __forceinline__ f32x4 mfma16(bf16x8 a, bf16x8 b, f32x4 c) {
  return __builtin_amdgcn_mfma_f32_16x16x32_bf16(a, b, c, 0, 0, 0);
}

static __device__ __forceinline__ float fexp2(float x) {
  return __builtin_amdgcn_exp2f(x);  // raw v_exp_f32; args bounded ~[-30,30]
}

// Async global->LDS, 16B per lane; lane i lands at dst + i*16B (m97 pattern).
static __device__ __forceinline__ void gl_lds16(const bf16* g, bf16* l) {
  __builtin_amdgcn_global_load_lds(
      (const __attribute__((address_space(1))) void*)g,
      (__attribute__((address_space(3))) void*)l, 16, 0, 0);
}

// ---------------------------------------------------------------------------
// Fused weight transposes: 6 jobs in one launch.  out[z][c][r] = in[z][r][c].
// ---------------------------------------------------------------------------
struct TrTab {
  const float* src[6];
  bf16* dst[6];
  int R[6], C[6], ntx[6], nty[6];
  int base[7];
};

__global__ __launch_bounds__(256) void tr6_kernel(TrTab tab) {
  int bid = blockIdx.x;
  int j = 0;
  while (j < 5 && bid >= tab.base[j + 1]) ++j;
  const int local = bid - tab.base[j];
  const int R = tab.R[j], C = tab.C[j];
  const int ntx = tab.ntx[j];
  const int per_z = ntx * tab.nty[j];
  const int z = local / per_z;
  const int rem = local - z * per_z;
  const int by = rem / ntx, bx = rem - by * ntx;
  const float* in = tab.src[j];
  bf16* out = tab.dst[j];

  __shared__ bf16 tile[32][33];
  const size_t zoff = (size_t)z * R * C;
  const int tx = threadIdx.x & 31, ty = threadIdx.x >> 5;  // ty 0..7
  const int x = bx * 32 + tx;
  const int y0 = by * 32;
#pragma unroll
  for (int jj = 0; jj < 4; ++jj)
    tile[ty + jj * 8][tx] = (bf16)in[zoff + (size_t)(y0 + ty + jj * 8) * C + x];
  __syncthreads();
  const int x2 = y0 + tx;
  const int y2 = bx * 32;
#pragma unroll
  for (int jj = 0; jj < 4; ++jj)
    out[zoff + (size_t)(y2 + ty + jj * 8) * R + x2] = tile[tx][ty + jj * 8];
}

// bf16 batched transpose (for V -> V^T).
__global__ __launch_bounds__(256) void trb_kernel(const bf16* __restrict__ inp,
                                                  bf16* __restrict__ out,
                                                  int R, int C) {
  __shared__ bf16 tile[32][33];
  const size_t zoff = (size_t)blockIdx.z * R * C;
  const int tx = threadIdx.x & 31, ty = threadIdx.x >> 5;
  const int x = blockIdx.x * 32 + tx;
  const int y0 = blockIdx.y * 32;
#pragma unroll
  for (int j = 0; j < 4; ++j)
    tile[ty + j * 8][tx] = inp[zoff + (size_t)(y0 + ty + j * 8) * C + x];
  __syncthreads();
  const int x2 = y0 + tx;
  const int y2 = blockIdx.x * 32;
#pragma unroll
  for (int j = 0; j < 4; ++j)
    out[zoff + (size_t)(y2 + ty + j * 8) * R + x2] = tile[tx][ty + j * 8];
}

// ---------------------------------------------------------------------------
// LayerNorm over D=1024; one block per row; fp32 in, bf16 out.
// ---------------------------------------------------------------------------
__global__ __launch_bounds__(256) void ln_kernel(const float* __restrict__ inp,
                                                 const float* __restrict__ g,
                                                 const float* __restrict__ bt,
                                                 bf16* __restrict__ outp) {
  const int row = blockIdx.x;
  const int t = threadIdx.x;
  f32x4 v = ((const f32x4*)inp)[row * 256 + t];
  float s = v[0] + v[1] + v[2] + v[3];
  float sq = v[0] * v[0] + v[1] * v[1] + v[2] * v[2] + v[3] * v[3];
#pragma unroll
  for (int off = 32; off > 0; off >>= 1) {
    s += __shfl_xor(s, off);
    sq += __shfl_xor(sq, off);
  }
  __shared__ float red[8];
  const int wave = t >> 6, lane = t & 63;
  if (lane == 0) {
    red[wave] = s;
    red[wave + 4] = sq;
  }
  __syncthreads();
  s = red[0] + red[1] + red[2] + red[3];
  sq = red[4] + red[5] + red[6] + red[7];
  const float mu = s * (1.0f / 1024.0f);
  const float var = sq * (1.0f / 1024.0f) - mu * mu;
  const float rstd = rsqrtf(fmaxf(var, 0.0f) + 1e-5f);
  f32x4 gg = ((const f32x4*)g)[t];
  f32x4 bb = ((const f32x4*)bt)[t];
  bf16 o[4];
#pragma unroll
  for (int i = 0; i < 4; ++i)
    o[i] = (bf16)((v[i] - mu) * rstd * gg[i] + bb[i]);
  *(uint2*)&outp[(size_t)row * 1024 + 4 * t] = *(uint2*)o;
}

// ---------------------------------------------------------------------------
// GEMM C = A @ Bt^T.  Tile 128 x BN (BN=128 or 64), BK=64, 4 waves 2x2.
// m99-style double buffer, single barrier per K-tile.  XOR chunk swizzle ->
// 0 bank conflicts.  T1: bijective XCD chunk-swizzle of the block id so each
// XCD owns contiguous m-rows (A-panel sharing within one L2; per-XCD per-
// K-step working set ~200 KB << 4 MB L2).  All grids have nwg % 8 == 0.
// ---------------------------------------------------------------------------
enum { EPI_QKV = 0, EPI_O = 1, EPI_FF1 = 2, EPI_FF2 = 3 };

template <int EPI, bool NARROW>
__global__ __launch_bounds__(256) void gemm_bt(
    const bf16* __restrict__ A, const bf16* __restrict__ Bt, const int K,
    const float* __restrict__ bias, const float* __restrict__ res,
    bf16* __restrict__ outB, float* __restrict__ outF) {
  constexpr int BN = NARROW ? 64 : 128;
  constexpr int NI = NARROW ? 2 : 4;
  constexpr int BCH = BN / 32;  // B-chunks staged per wave
  __shared__ __align__(16) bf16 sA[2][128 * 64];
  __shared__ __align__(16) bf16 sB[2][BN * 64];
  const int t = threadIdx.x;
  const int lane = t & 63, wave = t >> 6;
  const int quad = lane >> 4, l15 = lane & 15;
  const int wr = wave >> 1, wc = wave & 1;

  // XCD chunk swizzle: dispatch id lin runs on XCD (lin&7); remap so XCD k
  // executes a contiguous tile range (n-fastest => same-m tiles colocate).
  const int gx = gridDim.x;
  const int nwg = gx * gridDim.y;
  const int lin = blockIdx.y * gx + blockIdx.x;
  const int sw = (lin & 7) * (nwg >> 3) + (lin >> 3);
  const int m0 = (sw / gx) * 128, n0 = (sw % gx) * BN;

  const int srow = lane >> 3;
  const int scol = ((lane & 7) ^ srow) * 8;

  // per-thread staging pointers (advance by 64 elems per K-tile)
  const bf16* aPtr[4];
#pragma unroll
  for (int c = 0; c < 4; ++c)
    aPtr[c] = A + (size_t)(m0 + wave * 32 + c * 8 + srow) * K + scol;
  const bf16* bPtr[BCH];
#pragma unroll
  for (int c = 0; c < BCH; ++c)
    bPtr[c] = Bt + (size_t)(n0 + wave * (BCH * 8) + c * 8 + srow) * K + scol;

  f32x4 acc[4][NI];
#pragma unroll
  for (int i = 0; i < 4; ++i)
#pragma unroll
    for (int j = 0; j < NI; ++j) acc[i][j] = {0.f, 0.f, 0.f, 0.f};

  const int niter = K >> 6;
  // prologue: stage tile 0 into buffer 0
#pragma unroll
  for (int c = 0; c < 4; ++c)
    gl_lds16(aPtr[c], &sA[0][(wave * 4 + c) * 512]);
#pragma unroll
  for (int c = 0; c < BCH; ++c)
    gl_lds16(bPtr[c], &sB[0][(wave * BCH + c) * 512]);

  for (int it = 0; it < niter; ++it) {
    const int cur = it & 1, nxt = cur ^ 1;
    __syncthreads();  // drains cur-buf DMA; prior reads of nxt-buf complete
    if (it + 1 < niter) {
      const int off = (it + 1) * 64;
#pragma unroll
      for (int c = 0; c < 4; ++c)
        gl_lds16(aPtr[c] + off, &sA[nxt][(wave * 4 + c) * 512]);
#pragma unroll
      for (int c = 0; c < BCH; ++c)
        gl_lds16(bPtr[c] + off, &sB[nxt][(wave * BCH + c) * 512]);
    }
#pragma unroll
    for (int ks = 0; ks < 2; ++ks) {
      bf16x8 af[4], bfr[NI];
#pragma unroll
      for (int mi = 0; mi < 4; ++mi) {
        const int row = wr * 64 + mi * 16 + l15;
        const int col = ((ks * 4 + quad) ^ (row & 7)) * 8;
        af[mi] = *(const bf16x8*)&sA[cur][row * 64 + col];
      }
#pragma unroll
      for (int ni = 0; ni < NI; ++ni) {
        const int row = wc * (BN / 2) + ni * 16 + l15;
        const int col = ((ks * 4 + quad) ^ (row & 7)) * 8;
        bfr[ni] = *(const bf16x8*)&sB[cur][row * 64 + col];
      }
#pragma unroll
      for (int mi = 0; mi < 4; ++mi)
#pragma unroll
        for (int ni = 0; ni < NI; ++ni)
          acc[mi][ni] = mfma16(af[mi], bfr[ni], acc[mi][ni]);
    }
  }

  // C/D layout: within a 16x16 tile, row(m) = quad*4 + r, col(n) = l15.
#pragma unroll
  for (int mi = 0; mi < 4; ++mi) {
#pragma unroll
    for (int ni = 0; ni < NI; ++ni) {
      const int n = n0 + wc * (BN / 2) + ni * 16 + l15;
#pragma unroll
      for (int r = 0; r < 4; ++r) {
        const int m = m0 + wr * 64 + mi * 16 + quad * 4 + r;
        float v = acc[mi][ni][r];
        if constexpr (EPI == EPI_QKV) {
          const int which = n >> 10, nn = n & 1023;
          const int h = nn >> 6, e = nn & 63;
          const int b = m >> 11, s2 = m & 2047;
          outB[(size_t)which * 4194304 +
               ((size_t)(b * 16 + h) * 2048 + s2) * 64 + e] = (bf16)v;
        } else if constexpr (EPI == EPI_O) {
          v += bias[n] + res[(size_t)m * 1024 + n];
          outF[(size_t)m * 1024 + n] = v;  // fp32 hidden
        } else if constexpr (EPI == EPI_FF1) {
          v += bias[n];
          v = 0.5f * v * (1.0f + erff(v * 0.70710678118654752f));  // exact GELU
          outB[(size_t)m * 4096 + n] = (bf16)v;
        } else {  // EPI_FF2: hidden + ff -> fp32 OUTPUT
          v += bias[n] + res[(size_t)m * 1024 + n];
          outF[(size_t)m * 1024 + n] = v;
        }
      }
    }
  }
}

// ---------------------------------------------------------------------------
// Flash attention, non-causal, no max-shift (s/8 ~ N(0,1): exp2 safe).
// Block = 128 queries of one (b,h), 512 threads = 8 waves.
// Split-K: waves 0-3 do keys [0,1024), waves 4-7 keys [1024,2048); partials
// (o, l) merge via LDS at the end (no rescale needed -- no running max).
// T1 swizzle: q-blocks of the same (b,h) colocate on one XCD (shared K/V).
// ---------------------------------------------------------------------------
__global__ __launch_bounds__(512, 4) void attn_kernel(
    const bf16* __restrict__ q, const bf16* __restrict__ k,
    const bf16* __restrict__ vt, bf16* __restrict__ ao) {
  __shared__ __align__(16) bf16 sP[256 * 72];    // 36 KB: Q stage -> P -> merge
  __shared__ __align__(16) bf16 sK[2][64 * 64];  // 16 KB
  __shared__ __align__(16) bf16 sV[2][64 * 64];  // 16 KB  (V^T tiles [e][key])
  const int t = threadIdx.x;
  const int lane = t & 63, wave = t >> 6;  // wave 0..7
  const int wq = wave & 3, kh = wave >> 2;
  const int quad = lane >> 4, l15 = lane & 15;

  // XCD chunk swizzle (nwg = 16*32 = 512; chunk 64 = 4 bh-groups per XCD)
  const int lin = blockIdx.y * 16 + blockIdx.x;
  const int sw = (lin & 7) * 64 + (lin >> 3);
  const int q0 = (sw & 15) * 128;
  const int bh = sw >> 4, b = bh >> 4, h = bh & 15;

  const bf16* Q  = q  + (size_t)bh * 2048 * 64;
  const bf16* Kp = k  + (size_t)bh * 2048 * 64 + (size_t)kh * 1024 * 64;
  const bf16* Vt = vt + (size_t)bh * 64 * 2048 + kh * 1024;
  const int srow = lane >> 3;
  const int scol = ((lane & 7) ^ srow) * 8;
  const float SCL = 0.125f * 1.4426950408889634f;  // 1/8 * log2(e)

  // stage Q 128x64 into sP front at stride 64 (16 chunks of 8 rows)
#pragma unroll
  for (int c = 0; c < 2; ++c) {
    const int chunk = wave * 2 + c;  // 0..15
    const int row = chunk * 8 + srow;
    gl_lds16(&Q[(size_t)(q0 + row) * 64 + scol], &sP[chunk * 512]);
  }
  __syncthreads();
  bf16x8 qf[2][2];  // B-operand frags: queries wq*32 + mi*16 + l15
#pragma unroll
  for (int mi = 0; mi < 2; ++mi)
#pragma unroll
    for (int ks = 0; ks < 2; ++ks) {
      const int row = wq * 32 + mi * 16 + l15;
      const int col = ((ks * 4 + quad) ^ (row & 7)) * 8;
      qf[mi][ks] = *(const bf16x8*)&sP[row * 64 + col];
    }
  __syncthreads();  // qf loaded everywhere before P writes clobber sP

  f32x4 o[2][4];
  float ls[2] = {0.f, 0.f};
#pragma unroll
  for (int mi = 0; mi < 2; ++mi)
#pragma unroll
    for (int ne = 0; ne < 4; ++ne) o[mi][ne] = {0.f, 0.f, 0.f, 0.f};

  for (int kb = 0; kb < 16; ++kb) {
    const int kbase = kb * 64;
    __syncthreads();  // prior-iter sK/sV frag reads complete
#pragma unroll
    for (int c = 0; c < 2; ++c) {
      const int chunk = wq * 2 + c;  // 0..7 within this half's buffers
      const int row = chunk * 8 + srow;
      gl_lds16(&Kp[(size_t)(kbase + row) * 64 + scol], &sK[kh][chunk * 512]);
      gl_lds16(&Vt[(size_t)row * 2048 + kbase + scol], &sV[kh][chunk * 512]);
    }
    __syncthreads();

    // S^T = K Q^T : D[key = ni*16+quad*4+r][query = wq*32+mi*16+l15]
    f32x4 s[4][2];
#pragma unroll
    for (int ni = 0; ni < 4; ++ni)
#pragma unroll
      for (int mi = 0; mi < 2; ++mi) s[ni][mi] = {0.f, 0.f, 0.f, 0.f};
#pragma unroll
    for (int ks = 0; ks < 2; ++ks) {
      bf16x8 kf[4];
#pragma unroll
      for (int ni = 0; ni < 4; ++ni) {
        const int row = ni * 16 + l15;
        const int col = ((ks * 4 + quad) ^ (row & 7)) * 8;
        kf[ni] = *(const bf16x8*)&sK[kh][row * 64 + col];
      }
#pragma unroll
      for (int ni = 0; ni < 4; ++ni)
#pragma unroll
        for (int mi = 0; mi < 2; ++mi)
          s[ni][mi] = mfma16(kf[ni], qf[mi][ks], s[ni][mi]);
    }

    // p = exp2(s*SCL); 4 contiguous keys/reg -> b64 store; lane-partial sums
#pragma unroll
    for (int mi = 0; mi < 2; ++mi)
#pragma unroll
      for (int ni = 0; ni < 4; ++ni) {
        bf16x4 p4;
#pragma unroll
        for (int r = 0; r < 4; ++r) {
          const float p = fexp2(s[ni][mi][r] * SCL);
          ls[mi] += p;
          p4[r] = (bf16)p;
        }
        *(bf16x4*)&sP[(wave * 32 + mi * 16 + l15) * 72 + ni * 16 + quad * 4] =
            p4;
      }

    // O += P @ V  (sP rows are wave-private; no barrier needed)
#pragma unroll
    for (int ksb = 0; ksb < 2; ++ksb) {
      bf16x8 vf[4];
#pragma unroll
      for (int ne = 0; ne < 4; ++ne) {
        const int row = ne * 16 + l15;
        const int col = ((ksb * 4 + quad) ^ (row & 7)) * 8;
        vf[ne] = *(const bf16x8*)&sV[kh][row * 64 + col];
      }
#pragma unroll
      for (int mi = 0; mi < 2; ++mi) {
        const bf16x8 pf = *(const bf16x8*)&sP[(wave * 32 + mi * 16 + l15) * 72 +
                                              ksb * 32 + quad * 8];
#pragma unroll
        for (int ne = 0; ne < 4; ++ne)
          o[mi][ne] = mfma16(pf, vf[ne], o[mi][ne]);
      }
    }
  }

  // reduce lane-partial sums over quads: every lane gets its query's total
#pragma unroll
  for (int mi = 0; mi < 2; ++mi) {
    ls[mi] += __shfl_xor(ls[mi], 16);
    ls[mi] += __shfl_xor(ls[mi], 32);
  }

  // merge key halves: kh=1 publishes (o, l); kh=0 combines and writes out
  float* mo = (float*)sP;        // [4 wq][64 lane][32 floats]
  float* ml = (float*)sK;        // [4 wq][64 lane][2]
  __syncthreads();  // all PV reads of sP/sK done before scratch reuse
  if (kh == 1) {
    const int base = (wq * 64 + lane) * 32;
#pragma unroll
    for (int mi = 0; mi < 2; ++mi)
#pragma unroll
      for (int ne = 0; ne < 4; ++ne)
        *(f32x4*)&mo[base + (mi * 4 + ne) * 4] = o[mi][ne];
    ml[(wq * 64 + lane) * 2 + 0] = ls[0];
    ml[(wq * 64 + lane) * 2 + 1] = ls[1];
  }
  __syncthreads();
  if (kh == 0) {
    const int base = (wq * 64 + lane) * 32;
#pragma unroll
    for (int mi = 0; mi < 2; ++mi) {
#pragma unroll
      for (int ne = 0; ne < 4; ++ne) {
        const f32x4 add = *(const f32x4*)&mo[base + (mi * 4 + ne) * 4];
#pragma unroll
        for (int r = 0; r < 4; ++r) o[mi][ne][r] += add[r];
      }
      ls[mi] += ml[(wq * 64 + lane) * 2 + mi];
      ls[mi] = 1.0f / fmaxf(ls[mi], 1e-30f);
    }
#pragma unroll
    for (int mi = 0; mi < 2; ++mi) {
      float linv[4];
#pragma unroll
      for (int r = 0; r < 4; ++r) linv[r] = __shfl(ls[mi], quad * 4 + r);
#pragma unroll
      for (int ne = 0; ne < 4; ++ne)
#pragma unroll
        for (int r = 0; r < 4; ++r) {
          const int row = q0 + wq * 32 + mi * 16 + quad * 4 + r;
          const int col = h * 64 + ne * 16 + l15;
          ao[((size_t)(b * 2048 + row)) * 1024 + col] =
              (bf16)(o[mi][ne][r] * linv[r]);
        }
    }
  }
}

// ---------------------------------------------------------------------------
extern "C" void kernel_launch(void* const* d_in, const int* in_sizes, int n_in,
                              void* d_out, int out_size, void* d_ws,
                              size_t ws_size, hipStream_t stream) {
  const float* x    = (const float*)d_in[0];
  const float* Wq   = (const float*)d_in[1];
  const float* Wk   = (const float*)d_in[2];
  const float* Wv   = (const float*)d_in[3];
  const float* Wo   = (const float*)d_in[4];
  const float* bo   = (const float*)d_in[5];
  const float* ln1g = (const float*)d_in[6];
  const float* ln1b = (const float*)d_in[7];
  const float* ln2g = (const float*)d_in[8];
  const float* ln2b = (const float*)d_in[9];
  const float* W1   = (const float*)d_in[10];
  const float* b1   = (const float*)d_in[11];
  const float* W2   = (const float*)d_in[12];
  const float* b2   = (const float*)d_in[13];

  char* ws = (char*)d_ws;
  const size_t MB = 1ull << 20;
  bf16* QKVT = (bf16*)(ws);              // [3072][1024]: WqT,WkT,WvT stacked
  bf16* WqT  = QKVT;
  bf16* WkT  = (bf16*)(ws + 2 * MB);
  bf16* WvT  = (bf16*)(ws + 4 * MB);
  bf16* WoT  = (bf16*)(ws + 6 * MB);     // [1024][1024]
  bf16* W1T  = (bf16*)(ws + 8 * MB);     // [4096][1024]
  bf16* W2T  = (bf16*)(ws + 16 * MB);    // [1024][4096]
  bf16* sh8  = (bf16*)(ws + 24 * MB);    // shared slot: xn -> aoc -> hn
  bf16* qb   = (bf16*)(ws + 32 * MB);    // [b][h][s][e]
  bf16* kb   = (bf16*)(ws + 40 * MB);
  bf16* vb   = (bf16*)(ws + 48 * MB);
  bf16* vtb  = (bf16*)(ws + 56 * MB);    // [b][h][e][s]
  bf16* h1   = (bf16*)(ws + 32 * MB);    // [4096][4096] (after attn)
  float* hid = (float*)(ws + 64 * MB);   // fp32 hidden; peak 80 MB

  const dim3 blk(256);

  // fused weight transposes: 6 jobs, one launch
  TrTab tab;
  const float* srcs[6] = {Wq, Wk, Wv, Wo, W1, W2};
  bf16* dsts[6] = {WqT, WkT, WvT, WoT, W1T, W2T};
  const int Rs[6] = {1024, 1024, 1024, 1024, 1024, 4096};
  const int Cs[6] = {64, 64, 64, 1024, 4096, 1024};
  const int Zs[6] = {16, 16, 16, 1, 1, 1};
  int base = 0;
  for (int j = 0; j < 6; ++j) {
    tab.src[j] = srcs[j];
    tab.dst[j] = dsts[j];
    tab.R[j] = Rs[j];
    tab.C[j] = Cs[j];
    tab.ntx[j] = Cs[j] / 32;
    tab.nty[j] = Rs[j] / 32;
    tab.base[j] = base;
    base += (Cs[j] / 32) * (Rs[j] / 32) * Zs[j];
  }
  tab.base[6] = base;  // 12288
  tr6_kernel<<<base, blk, 0, stream>>>(tab);

  ln_kernel<<<4096, blk, 0, stream>>>(x, ln1g, ln1b, sh8);              // xn
  gemm_bt<EPI_QKV, false><<<dim3(24, 32), blk, 0, stream>>>(
      sh8, QKVT, 1024, nullptr, nullptr, qb, nullptr);
  trb_kernel<<<dim3(2, 64, 32), blk, 0, stream>>>(vb, vtb, 2048, 64);
  attn_kernel<<<dim3(16, 32), dim3(512), 0, stream>>>(qb, kb, vtb, sh8);
  gemm_bt<EPI_O, false><<<dim3(8, 32), blk, 0, stream>>>(
      sh8, WoT, 1024, bo, x, nullptr, hid);
  ln_kernel<<<4096, blk, 0, stream>>>(hid, ln2g, ln2b, sh8);            // hn
  gemm_bt<EPI_FF1, false><<<dim3(32, 32), blk, 0, stream>>>(
      sh8, W1T, 1024, b1, nullptr, h1, nullptr);
  gemm_bt<EPI_FF2, true><<<dim3(16, 32), blk, 0, stream>>>(
      h1, W2T, 4096, b2, hid, nullptr, (float*)d_out);

  (void)in_sizes; (void)n_in; (void)out_size; (void)ws_size;
}

// Round 5
// 351.771 us; speedup vs baseline: 1.0350x; 1.0156x over previous
//
#include <hip/hip_runtime.h>
#include <hip/hip_bf16.h>

typedef __bf16 bf16;
typedef __bf16 bf16x4 __attribute__((ext_vector_type(4)));
typedef __bf16 bf16x8 __attribute__((ext_vector_type(8)));
typedef float  f32x4  __attribute__((ext_vector_type(4)));

static __device__ __forceinline__ f32x4 mfma16(bf16x8 a, bf16x8 b, f32x4 c) {
  return __builtin_amdgcn_mfma_f32_16x16x32_bf16(a, b, c, 0, 0, 0);
}

static __device__ __forceinline__ float fexp2(float x) {
  return __builtin_amdgcn_exp2f(x);  // raw v_exp_f32; args bounded ~[-30,30]
}

// Async global->LDS, 16B per lane; lane i lands at dst + i*16B (m97 pattern).
static __device__ __forceinline__ void gl_lds16(const bf16* g, bf16* l) {
  __builtin_amdgcn_global_load_lds(
      (const __attribute__((address_space(1))) void*)g,
      (__attribute__((address_space(3))) void*)l, 16, 0, 0);
}

// ---------------------------------------------------------------------------
// Fused weight transposes: 6 jobs in one launch.  out[z][c][r] = in[z][r][c].
// ---------------------------------------------------------------------------
struct TrTab {
  const float* src[6];
  bf16* dst[6];
  int R[6], C[6], ntx[6], nty[6];
  int base[7];
};

__global__ __launch_bounds__(256) void tr6_kernel(TrTab tab) {
  int bid = blockIdx.x;
  int j = 0;
  while (j < 5 && bid >= tab.base[j + 1]) ++j;
  const int local = bid - tab.base[j];
  const int R = tab.R[j], C = tab.C[j];
  const int ntx = tab.ntx[j];
  const int per_z = ntx * tab.nty[j];
  const int z = local / per_z;
  const int rem = local - z * per_z;
  const int by = rem / ntx, bx = rem - by * ntx;
  const float* in = tab.src[j];
  bf16* out = tab.dst[j];

  __shared__ bf16 tile[32][33];
  const size_t zoff = (size_t)z * R * C;
  const int tx = threadIdx.x & 31, ty = threadIdx.x >> 5;  // ty 0..7
  const int x = bx * 32 + tx;
  const int y0 = by * 32;
#pragma unroll
  for (int jj = 0; jj < 4; ++jj)
    tile[ty + jj * 8][tx] = (bf16)in[zoff + (size_t)(y0 + ty + jj * 8) * C + x];
  __syncthreads();
  const int x2 = y0 + tx;
  const int y2 = bx * 32;
#pragma unroll
  for (int jj = 0; jj < 4; ++jj)
    out[zoff + (size_t)(y2 + ty + jj * 8) * R + x2] = tile[tx][ty + jj * 8];
}

// bf16 batched transpose (for V -> V^T).
__global__ __launch_bounds__(256) void trb_kernel(const bf16* __restrict__ inp,
                                                  bf16* __restrict__ out,
                                                  int R, int C) {
  __shared__ bf16 tile[32][33];
  const size_t zoff = (size_t)blockIdx.z * R * C;
  const int tx = threadIdx.x & 31, ty = threadIdx.x >> 5;
  const int x = blockIdx.x * 32 + tx;
  const int y0 = blockIdx.y * 32;
#pragma unroll
  for (int j = 0; j < 4; ++j)
    tile[ty + j * 8][tx] = inp[zoff + (size_t)(y0 + ty + j * 8) * C + x];
  __syncthreads();
  const int x2 = y0 + tx;
  const int y2 = blockIdx.x * 32;
#pragma unroll
  for (int j = 0; j < 4; ++j)
    out[zoff + (size_t)(y2 + ty + j * 8) * R + x2] = tile[tx][ty + j * 8];
}

// ---------------------------------------------------------------------------
// LayerNorm over D=1024; one block per row; fp32 in, bf16 out.
// ---------------------------------------------------------------------------
__global__ __launch_bounds__(256) void ln_kernel(const float* __restrict__ inp,
                                                 const float* __restrict__ g,
                                                 const float* __restrict__ bt,
                                                 bf16* __restrict__ outp) {
  const int row = blockIdx.x;
  const int t = threadIdx.x;
  f32x4 v = ((const f32x4*)inp)[row * 256 + t];
  float s = v[0] + v[1] + v[2] + v[3];
  float sq = v[0] * v[0] + v[1] * v[1] + v[2] * v[2] + v[3] * v[3];
#pragma unroll
  for (int off = 32; off > 0; off >>= 1) {
    s += __shfl_xor(s, off);
    sq += __shfl_xor(sq, off);
  }
  __shared__ float red[8];
  const int wave = t >> 6, lane = t & 63;
  if (lane == 0) {
    red[wave] = s;
    red[wave + 4] = sq;
  }
  __syncthreads();
  s = red[0] + red[1] + red[2] + red[3];
  sq = red[4] + red[5] + red[6] + red[7];
  const float mu = s * (1.0f / 1024.0f);
  const float var = sq * (1.0f / 1024.0f) - mu * mu;
  const float rstd = rsqrtf(fmaxf(var, 0.0f) + 1e-5f);
  f32x4 gg = ((const f32x4*)g)[t];
  f32x4 bb = ((const f32x4*)bt)[t];
  bf16 o[4];
#pragma unroll
  for (int i = 0; i < 4; ++i)
    o[i] = (bf16)((v[i] - mu) * rstd * gg[i] + bb[i]);
  *(uint2*)&outp[(size_t)row * 1024 + 4 * t] = *(uint2*)o;
}

// ---------------------------------------------------------------------------
// GEMM epilogue selectors.
// ---------------------------------------------------------------------------
enum { EPI_QKV = 0, EPI_O = 1, EPI_FF1 = 2, EPI_FF2 = 3 };

#define VMW(N) asm volatile("s_waitcnt vmcnt(" #N ")" ::: "memory")
#define BARR                        \
  do {                              \
    __builtin_amdgcn_s_barrier();   \
    asm volatile("" ::: "memory");  \
  } while (0)

// ---------------------------------------------------------------------------
// 256x256 8-phase GEMM, m201-faithful schedule.  BK=64, 512 thr = 8 waves
// (2M x 4N), LDS 128 KB (2 buffers x [A 256x64 | B 256x64]).
// Per K-tile: 4 phases {ds_read new frags; stage 1 half-tile; [ph3: vmcnt];
// barrier; lgkmcnt(0); setprio(1); 16 MFMA; setprio(0); barrier}.
// Staging runs 7 half-tiles ahead in consumption order A0,B0,B1,A1 (stream
// ht g+7 issued at global phase g), so ONE vmcnt(6) per K-tile (at ph3)
// guarantees the whole next K-tile resident with 3 ht (6 loads) in flight.
// B0 frags are HELD in regs from ph0 to ph3 (no LDS re-read) -- required
// for race-freedom: ph2(t) overwrites buf[cur].B0 with B0(t+2).
// Ledger (verified): boundary at ph3(t): <=7 ht outstanding; vmcnt(6)
// retires through A1(t+1); every region overwrite >=1 barrier after last
// read.  Epilogue: ni-innermost stores -> contiguous 128B runs per row.
// XCD swizzle: per-XCD 4x(gx/2) sub-rectangle (requires gridDim.y==16).
// ---------------------------------------------------------------------------
template <int EPI>
__global__ __launch_bounds__(512) void gemm256(
    const bf16* __restrict__ A, const bf16* __restrict__ Bt, const int K,
    const float* __restrict__ bias, bf16* __restrict__ outB) {
  __shared__ __align__(16) bf16 sA[2][256 * 64];  // 64 KB
  __shared__ __align__(16) bf16 sB[2][256 * 64];  // 64 KB
  const int t = threadIdx.x;
  const int lane = t & 63, wave = t >> 6;
  const int quad = lane >> 4, l15 = lane & 15;
  const int wm = wave >> 2, wn = wave & 3;  // wave grid 2(M) x 4(N)

  // XCD sub-rect swizzle: xcd = lin&7 owns m-blocks [(xcd&3)*4,+4) x
  // n-blocks [(xcd>>2)*gx/2,+gx/2).  Bijective for gy==16, gx even.
  const int gx = gridDim.x;
  const int lin = blockIdx.y * gx + blockIdx.x;
  const int xcd = lin & 7, idx = lin >> 3;
  const int NBX = gx >> 1;
  const int m0 = ((xcd & 3) * 4 + (idx & 3)) * 256;
  const int n0 = ((xcd >> 2) * NBX + (idx >> 2)) * 256;

  const int srow = lane >> 3;
  const int scol = ((lane & 7) ^ srow) * 8;  // pre-swizzled global source
  const int bch = (wave & 3) + (wave >> 2) * 8;  // B-chunk id base

  // staging source pointers (advance by ko elems per K-tile)
  const bf16* aS0 = A + (size_t)(m0 + wave * 8 + srow) * K + scol;
  const bf16* aS1 = aS0 + (size_t)64 * K;
  const bf16* bS0 = Bt + (size_t)(n0 + bch * 8 + srow) * K + scol;
  const bf16* bS1 = bS0 + (size_t)32 * K;
  const size_t rsk = (size_t)128 * K;  // +16 chunks (128 rows)

  // half-tile stagers: 2 x global_load_lds each; chunk = 8 rows x 64 cols.
  auto stA0 = [&](int buf, int ko) {
    gl_lds16(aS0 + ko, &sA[buf][wave * 512]);
    gl_lds16(aS0 + ko + rsk, &sA[buf][(wave + 16) * 512]);
  };
  auto stB0 = [&](int buf, int ko) {
    gl_lds16(bS0 + ko, &sB[buf][bch * 512]);
    gl_lds16(bS0 + ko + rsk, &sB[buf][(bch + 16) * 512]);
  };
  auto stB1 = [&](int buf, int ko) {
    gl_lds16(bS1 + ko, &sB[buf][(bch + 4) * 512]);
    gl_lds16(bS1 + ko + rsk, &sB[buf][(bch + 20) * 512]);
  };
  auto stA1 = [&](int buf, int ko) {
    gl_lds16(aS1 + ko, &sA[buf][(wave + 8) * 512]);
    gl_lds16(aS1 + ko + rsk, &sA[buf][(wave + 24) * 512]);
  };

  f32x4 acc[8][4];
#pragma unroll
  for (int i = 0; i < 8; ++i)
#pragma unroll
    for (int j = 0; j < 4; ++j) acc[i][j] = {0.f, 0.f, 0.f, 0.f};

  bf16x8 af[4][2], bf0[2][2], bf1[2][2];

  auto ldA = [&](int buf, int mh) {  // 8 x ds_read_b128
#pragma unroll
    for (int i = 0; i < 4; ++i) {
      const int row = wm * 128 + mh * 64 + i * 16 + l15;
#pragma unroll
      for (int ks = 0; ks < 2; ++ks) {
        const int col = ((ks * 4 + quad) ^ (row & 7)) * 8;
        af[i][ks] = *(const bf16x8*)&sA[buf][row * 64 + col];
      }
    }
  };
  auto ldB = [&](int buf, int nh, bf16x8 (&bfm)[2][2]) {  // 4 x ds_read_b128
#pragma unroll
    for (int j = 0; j < 2; ++j) {
      const int row = wn * 64 + nh * 32 + j * 16 + l15;
#pragma unroll
      for (int ks = 0; ks < 2; ++ks) {
        const int col = ((ks * 4 + quad) ^ (row & 7)) * 8;
        bfm[j][ks] = *(const bf16x8*)&sB[buf][row * 64 + col];
      }
    }
  };
  auto mm = [&](int mh, int nh, bf16x8 (&bfm)[2][2]) {  // 16 MFMA cluster
    asm volatile("s_waitcnt lgkmcnt(0)" ::: "memory");
    __builtin_amdgcn_sched_barrier(0);
    __builtin_amdgcn_s_setprio(1);
#pragma unroll
    for (int ks = 0; ks < 2; ++ks)
#pragma unroll
      for (int i = 0; i < 4; ++i)
#pragma unroll
        for (int j = 0; j < 2; ++j)
          acc[mh * 4 + i][nh * 2 + j] =
              mfma16(af[i][ks], bfm[j][ks], acc[mh * 4 + i][nh * 2 + j]);
    __builtin_amdgcn_s_setprio(0);
    __builtin_amdgcn_sched_barrier(0);
  };

  // prologue: 7 half-tiles (all of t0, A0/B0/B1 of t1), then vmcnt(6).
  stA0(0, 0);
  stB0(0, 0);
  stB1(0, 0);
  stA1(0, 0);
  stA0(1, 64);
  stB0(1, 64);
  stB1(1, 64);
  VMW(6);
  BARR;

  const int NT = K >> 6;
#pragma unroll 1
  for (int it = 0; it < NT; ++it) {
    const int cur = it & 1, nxt = cur ^ 1;
    const int k1 = (it + 1) * 64, k2 = (it + 2) * 64;
    // ph0: reads A0+B0 (12 ds_reads); stages A1(t+1) -> buf nxt
    ldA(cur, 0);
    ldB(cur, 0, bf0);
    if (it + 1 < NT) stA1(nxt, k1);
    BARR;
    mm(0, 0, bf0);
    BARR;
    // ph1: reads B1 (4); stages A0(t+2) -> buf cur (A0 last read ph0)
    ldB(cur, 1, bf1);
    if (it + 2 < NT) stA0(cur, k2);
    BARR;
    mm(0, 1, bf1);
    BARR;
    // ph2: reads A1 (8); stages B0(t+2) -> buf cur (B0 last read ph0)
    ldA(cur, 1);
    if (it + 2 < NT) stB0(cur, k2);
    BARR;
    mm(1, 1, bf1);
    BARR;
    // ph3: no reads (A1 in af, B0 held in bf0); stages B1(t+2);
    // boundary wait: all of t+1 resident, 3 ht in flight.
    if (it + 2 < NT) {
      stB1(cur, k2);
      VMW(6);
    } else if (it + 1 < NT) {
      VMW(0);
    }
    BARR;
    mm(1, 0, bf0);
    BARR;
  }

  // Epilogue.  C/D per 16x16 tile: row(m) = quad*4 + r, col(n) = l15.
  // ni innermost -> per (mi,r) each wave stores a contiguous 128B run.
  float bv4[4] = {0.f, 0.f, 0.f, 0.f};
  if constexpr (EPI == EPI_FF1) {
#pragma unroll
    for (int ni = 0; ni < 4; ++ni) bv4[ni] = bias[n0 + wn * 64 + ni * 16 + l15];
  }
#pragma unroll
  for (int mi = 0; mi < 8; ++mi) {
#pragma unroll
    for (int r = 0; r < 4; ++r) {
      const int m = m0 + wm * 128 + mi * 16 + quad * 4 + r;
#pragma unroll
      for (int ni = 0; ni < 4; ++ni) {
        const int n = n0 + wn * 64 + ni * 16 + l15;
        float v = acc[mi][ni][r];
        if constexpr (EPI == EPI_QKV) {
          const int which = n >> 10, nn = n & 1023;
          const int h = nn >> 6, e = nn & 63;
          const int b = m >> 11, s2 = m & 2047;
          outB[(size_t)which * 4194304 +
               ((size_t)(b * 16 + h) * 2048 + s2) * 64 + e] = (bf16)v;
        } else {  // EPI_FF1
          v += bv4[ni];
          v = 0.5f * v * (1.0f + erff(v * 0.70710678118654752f));  // exact GELU
          outB[(size_t)m * 4096 + n] = (bf16)v;
        }
      }
    }
  }
}

// ---------------------------------------------------------------------------
// GEMM C = A @ Bt^T.  Tile 128 x BN (BN=128 or 64), BK=64, 4 waves 2x2.
// m99-style double buffer (proven).  No XCD swizzle (round-3 A/B: the
// m-chunked swizzle raised FF1 FETCH 41->70 MB; natural order is better).
// ---------------------------------------------------------------------------
template <int EPI, bool NARROW>
__global__ __launch_bounds__(256) void gemm_bt(
    const bf16* __restrict__ A, const bf16* __restrict__ Bt, const int K,
    const float* __restrict__ bias, const float* __restrict__ res,
    bf16* __restrict__ outB, float* __restrict__ outF) {
  constexpr int BN = NARROW ? 64 : 128;
  constexpr int NI = NARROW ? 2 : 4;
  constexpr int BCH = BN / 32;  // B-chunks staged per wave
  __shared__ __align__(16) bf16 sA[2][128 * 64];
  __shared__ __align__(16) bf16 sB[2][BN * 64];
  const int t = threadIdx.x;
  const int lane = t & 63, wave = t >> 6;
  const int quad = lane >> 4, l15 = lane & 15;
  const int wr = wave >> 1, wc = wave & 1;
  const int m0 = blockIdx.y * 128, n0 = blockIdx.x * BN;
  const int srow = lane >> 3;
  const int scol = ((lane & 7) ^ srow) * 8;

  // per-thread staging pointers (advance by 64 elems per K-tile)
  const bf16* aPtr[4];
#pragma unroll
  for (int c = 0; c < 4; ++c)
    aPtr[c] = A + (size_t)(m0 + wave * 32 + c * 8 + srow) * K + scol;
  const bf16* bPtr[BCH];
#pragma unroll
  for (int c = 0; c < BCH; ++c)
    bPtr[c] = Bt + (size_t)(n0 + wave * (BCH * 8) + c * 8 + srow) * K + scol;

  f32x4 acc[4][NI];
#pragma unroll
  for (int i = 0; i < 4; ++i)
#pragma unroll
    for (int j = 0; j < NI; ++j) acc[i][j] = {0.f, 0.f, 0.f, 0.f};

  const int niter = K >> 6;
  // prologue: stage tile 0 into buffer 0
#pragma unroll
  for (int c = 0; c < 4; ++c)
    gl_lds16(aPtr[c], &sA[0][(wave * 4 + c) * 512]);
#pragma unroll
  for (int c = 0; c < BCH; ++c)
    gl_lds16(bPtr[c], &sB[0][(wave * BCH + c) * 512]);

  for (int it = 0; it < niter; ++it) {
    const int cur = it & 1, nxt = cur ^ 1;
    __syncthreads();  // drains cur-buf DMA; prior reads of nxt-buf complete
    if (it + 1 < niter) {
      const int off = (it + 1) * 64;
#pragma unroll
      for (int c = 0; c < 4; ++c)
        gl_lds16(aPtr[c] + off, &sA[nxt][(wave * 4 + c) * 512]);
#pragma unroll
      for (int c = 0; c < BCH; ++c)
        gl_lds16(bPtr[c] + off, &sB[nxt][(wave * BCH + c) * 512]);
    }
#pragma unroll
    for (int ks = 0; ks < 2; ++ks) {
      bf16x8 af[4], bfr[NI];
#pragma unroll
      for (int mi = 0; mi < 4; ++mi) {
        const int row = wr * 64 + mi * 16 + l15;
        const int col = ((ks * 4 + quad) ^ (row & 7)) * 8;
        af[mi] = *(const bf16x8*)&sA[cur][row * 64 + col];
      }
#pragma unroll
      for (int ni = 0; ni < NI; ++ni) {
        const int row = wc * (BN / 2) + ni * 16 + l15;
        const int col = ((ks * 4 + quad) ^ (row & 7)) * 8;
        bfr[ni] = *(const bf16x8*)&sB[cur][row * 64 + col];
      }
#pragma unroll
      for (int mi = 0; mi < 4; ++mi)
#pragma unroll
        for (int ni = 0; ni < NI; ++ni)
          acc[mi][ni] = mfma16(af[mi], bfr[ni], acc[mi][ni]);
    }
  }

  // C/D layout: within a 16x16 tile, row(m) = quad*4 + r, col(n) = l15.
#pragma unroll
  for (int mi = 0; mi < 4; ++mi) {
#pragma unroll
    for (int ni = 0; ni < NI; ++ni) {
      const int n = n0 + wc * (BN / 2) + ni * 16 + l15;
#pragma unroll
      for (int r = 0; r < 4; ++r) {
        const int m = m0 + wr * 64 + mi * 16 + quad * 4 + r;
        float v = acc[mi][ni][r];
        if constexpr (EPI == EPI_QKV) {
          const int which = n >> 10, nn = n & 1023;
          const int h = nn >> 6, e = nn & 63;
          const int b = m >> 11, s2 = m & 2047;
          outB[(size_t)which * 4194304 +
               ((size_t)(b * 16 + h) * 2048 + s2) * 64 + e] = (bf16)v;
        } else if constexpr (EPI == EPI_O) {
          v += bias[n] + res[(size_t)m * 1024 + n];
          outF[(size_t)m * 1024 + n] = v;  // fp32 hidden
        } else if constexpr (EPI == EPI_FF1) {
          v += bias[n];
          v = 0.5f * v * (1.0f + erff(v * 0.70710678118654752f));  // exact GELU
          outB[(size_t)m * 4096 + n] = (bf16)v;
        } else {  // EPI_FF2: hidden + ff -> fp32 OUTPUT
          v += bias[n] + res[(size_t)m * 1024 + n];
          outF[(size_t)m * 1024 + n] = v;
        }
      }
    }
  }
}

// ---------------------------------------------------------------------------
// Flash attention, non-causal, no max-shift (s/8 ~ N(0,1): exp2 safe).
// Block = 128 queries of one (b,h), 512 threads = 8 waves.
// Split-K: waves 0-3 do keys [0,1024), waves 4-7 keys [1024,2048); partials
// (o, l) merge via LDS at the end (no rescale needed -- no running max).
// T1 swizzle: q-blocks of the same (b,h) colocate on one XCD (shared K/V).
// ---------------------------------------------------------------------------
__global__ __launch_bounds__(512, 4) void attn_kernel(
    const bf16* __restrict__ q, const bf16* __restrict__ k,
    const bf16* __restrict__ vt, bf16* __restrict__ ao) {
  __shared__ __align__(16) bf16 sP[256 * 72];    // 36 KB: Q stage -> P -> merge
  __shared__ __align__(16) bf16 sK[2][64 * 64];  // 16 KB
  __shared__ __align__(16) bf16 sV[2][64 * 64];  // 16 KB  (V^T tiles [e][key])
  const int t = threadIdx.x;
  const int lane = t & 63, wave = t >> 6;  // wave 0..7
  const int wq = wave & 3, kh = wave >> 2;
  const int quad = lane >> 4, l15 = lane & 15;

  // XCD chunk swizzle (nwg = 16*32 = 512; chunk 64 = 4 bh-groups per XCD)
  const int lin = blockIdx.y * 16 + blockIdx.x;
  const int sw = (lin & 7) * 64 + (lin >> 3);
  const int q0 = (sw & 15) * 128;
  const int bh = sw >> 4, b = bh >> 4, h = bh & 15;

  const bf16* Q  = q  + (size_t)bh * 2048 * 64;
  const bf16* Kp = k  + (size_t)bh * 2048 * 64 + (size_t)kh * 1024 * 64;
  const bf16* Vt = vt + (size_t)bh * 64 * 2048 + kh * 1024;
  const int srow = lane >> 3;
  const int scol = ((lane & 7) ^ srow) * 8;
  const float SCL = 0.125f * 1.4426950408889634f;  // 1/8 * log2(e)

  // stage Q 128x64 into sP front at stride 64 (16 chunks of 8 rows)
#pragma unroll
  for (int c = 0; c < 2; ++c) {
    const int chunk = wave * 2 + c;  // 0..15
    const int row = chunk * 8 + srow;
    gl_lds16(&Q[(size_t)(q0 + row) * 64 + scol], &sP[chunk * 512]);
  }
  __syncthreads();
  bf16x8 qf[2][2];  // B-operand frags: queries wq*32 + mi*16 + l15
#pragma unroll
  for (int mi = 0; mi < 2; ++mi)
#pragma unroll
    for (int ks = 0; ks < 2; ++ks) {
      const int row = wq * 32 + mi * 16 + l15;
      const int col = ((ks * 4 + quad) ^ (row & 7)) * 8;
      qf[mi][ks] = *(const bf16x8*)&sP[row * 64 + col];
    }
  __syncthreads();  // qf loaded everywhere before P writes clobber sP

  f32x4 o[2][4];
  float ls[2] = {0.f, 0.f};
#pragma unroll
  for (int mi = 0; mi < 2; ++mi)
#pragma unroll
    for (int ne = 0; ne < 4; ++ne) o[mi][ne] = {0.f, 0.f, 0.f, 0.f};

  for (int kb = 0; kb < 16; ++kb) {
    const int kbase = kb * 64;
    __syncthreads();  // prior-iter sK/sV frag reads complete
#pragma unroll
    for (int c = 0; c < 2; ++c) {
      const int chunk = wq * 2 + c;  // 0..7 within this half's buffers
      const int row = chunk * 8 + srow;
      gl_lds16(&Kp[(size_t)(kbase + row) * 64 + scol], &sK[kh][chunk * 512]);
      gl_lds16(&Vt[(size_t)row * 2048 + kbase + scol], &sV[kh][chunk * 512]);
    }
    __syncthreads();

    // S^T = K Q^T : D[key = ni*16+quad*4+r][query = wq*32+mi*16+l15]
    f32x4 s[4][2];
#pragma unroll
    for (int ni = 0; ni < 4; ++ni)
#pragma unroll
      for (int mi = 0; mi < 2; ++mi) s[ni][mi] = {0.f, 0.f, 0.f, 0.f};
#pragma unroll
    for (int ks = 0; ks < 2; ++ks) {
      bf16x8 kf[4];
#pragma unroll
      for (int ni = 0; ni < 4; ++ni) {
        const int row = ni * 16 + l15;
        const int col = ((ks * 4 + quad) ^ (row & 7)) * 8;
        kf[ni] = *(const bf16x8*)&sK[kh][row * 64 + col];
      }
#pragma unroll
      for (int ni = 0; ni < 4; ++ni)
#pragma unroll
        for (int mi = 0; mi < 2; ++mi)
          s[ni][mi] = mfma16(kf[ni], qf[mi][ks], s[ni][mi]);
    }

    // p = exp2(s*SCL); 4 contiguous keys/reg -> b64 store; lane-partial sums
#pragma unroll
    for (int mi = 0; mi < 2; ++mi)
#pragma unroll
      for (int ni = 0; ni < 4; ++ni) {
        bf16x4 p4;
#pragma unroll
        for (int r = 0; r < 4; ++r) {
          const float p = fexp2(s[ni][mi][r] * SCL);
          ls[mi] += p;
          p4[r] = (bf16)p;
        }
        *(bf16x4*)&sP[(wave * 32 + mi * 16 + l15) * 72 + ni * 16 + quad * 4] =
            p4;
      }

    // O += P @ V  (sP rows are wave-private; no barrier needed)
#pragma unroll
    for (int ksb = 0; ksb < 2; ++ksb) {
      bf16x8 vf[4];
#pragma unroll
      for (int ne = 0; ne < 4; ++ne) {
        const int row = ne * 16 + l15;
        const int col = ((ksb * 4 + quad) ^ (row & 7)) * 8;
        vf[ne] = *(const bf16x8*)&sV[kh][row * 64 + col];
      }
#pragma unroll
      for (int mi = 0; mi < 2; ++mi) {
        const bf16x8 pf = *(const bf16x8*)&sP[(wave * 32 + mi * 16 + l15) * 72 +
                                              ksb * 32 + quad * 8];
#pragma unroll
        for (int ne = 0; ne < 4; ++ne)
          o[mi][ne] = mfma16(pf, vf[ne], o[mi][ne]);
      }
    }
  }

  // reduce lane-partial sums over quads: every lane gets its query's total
#pragma unroll
  for (int mi = 0; mi < 2; ++mi) {
    ls[mi] += __shfl_xor(ls[mi], 16);
    ls[mi] += __shfl_xor(ls[mi], 32);
  }

  // merge key halves: kh=1 publishes (o, l); kh=0 combines and writes out
  float* mo = (float*)sP;        // [4 wq][64 lane][32 floats]
  float* ml = (float*)sK;        // [4 wq][64 lane][2]
  __syncthreads();  // all PV reads of sP/sK done before scratch reuse
  if (kh == 1) {
    const int base = (wq * 64 + lane) * 32;
#pragma unroll
    for (int mi = 0; mi < 2; ++mi)
#pragma unroll
      for (int ne = 0; ne < 4; ++ne)
        *(f32x4*)&mo[base + (mi * 4 + ne) * 4] = o[mi][ne];
    ml[(wq * 64 + lane) * 2 + 0] = ls[0];
    ml[(wq * 64 + lane) * 2 + 1] = ls[1];
  }
  __syncthreads();
  if (kh == 0) {
    const int base = (wq * 64 + lane) * 32;
#pragma unroll
    for (int mi = 0; mi < 2; ++mi) {
#pragma unroll
      for (int ne = 0; ne < 4; ++ne) {
        const f32x4 add = *(const f32x4*)&mo[base + (mi * 4 + ne) * 4];
#pragma unroll
        for (int r = 0; r < 4; ++r) o[mi][ne][r] += add[r];
      }
      ls[mi] += ml[(wq * 64 + lane) * 2 + mi];
      ls[mi] = 1.0f / fmaxf(ls[mi], 1e-30f);
    }
#pragma unroll
    for (int mi = 0; mi < 2; ++mi) {
      float linv[4];
#pragma unroll
      for (int r = 0; r < 4; ++r) linv[r] = __shfl(ls[mi], quad * 4 + r);
#pragma unroll
      for (int ne = 0; ne < 4; ++ne)
#pragma unroll
        for (int r = 0; r < 4; ++r) {
          const int row = q0 + wq * 32 + mi * 16 + quad * 4 + r;
          const int col = h * 64 + ne * 16 + l15;
          ao[((size_t)(b * 2048 + row)) * 1024 + col] =
              (bf16)(o[mi][ne][r] * linv[r]);
        }
    }
  }
}

// ---------------------------------------------------------------------------
extern "C" void kernel_launch(void* const* d_in, const int* in_sizes, int n_in,
                              void* d_out, int out_size, void* d_ws,
                              size_t ws_size, hipStream_t stream) {
  const float* x    = (const float*)d_in[0];
  const float* Wq   = (const float*)d_in[1];
  const float* Wk   = (const float*)d_in[2];
  const float* Wv   = (const float*)d_in[3];
  const float* Wo   = (const float*)d_in[4];
  const float* bo   = (const float*)d_in[5];
  const float* ln1g = (const float*)d_in[6];
  const float* ln1b = (const float*)d_in[7];
  const float* ln2g = (const float*)d_in[8];
  const float* ln2b = (const float*)d_in[9];
  const float* W1   = (const float*)d_in[10];
  const float* b1   = (const float*)d_in[11];
  const float* W2   = (const float*)d_in[12];
  const float* b2   = (const float*)d_in[13];

  char* ws = (char*)d_ws;
  const size_t MB = 1ull << 20;
  bf16* QKVT = (bf16*)(ws);              // [3072][1024]: WqT,WkT,WvT stacked
  bf16* WqT  = QKVT;
  bf16* WkT  = (bf16*)(ws + 2 * MB);
  bf16* WvT  = (bf16*)(ws + 4 * MB);
  bf16* WoT  = (bf16*)(ws + 6 * MB);     // [1024][1024]
  bf16* W1T  = (bf16*)(ws + 8 * MB);     // [4096][1024]
  bf16* W2T  = (bf16*)(ws + 16 * MB);    // [1024][4096]
  bf16* sh8  = (bf16*)(ws + 24 * MB);    // shared slot: xn -> aoc -> hn
  bf16* qb   = (bf16*)(ws + 32 * MB);    // [b][h][s][e]
  bf16* kb   = (bf16*)(ws + 40 * MB);
  bf16* vb   = (bf16*)(ws + 48 * MB);
  bf16* vtb  = (bf16*)(ws + 56 * MB);    // [b][h][e][s]
  bf16* h1   = (bf16*)(ws + 32 * MB);    // [4096][4096] (after attn)
  float* hid = (float*)(ws + 64 * MB);   // fp32 hidden; peak 80 MB

  const dim3 blk(256);

  // fused weight transposes: 6 jobs, one launch
  TrTab tab;
  const float* srcs[6] = {Wq, Wk, Wv, Wo, W1, W2};
  bf16* dsts[6] = {WqT, WkT, WvT, WoT, W1T, W2T};
  const int Rs[6] = {1024, 1024, 1024, 1024, 1024, 4096};
  const int Cs[6] = {64, 64, 64, 1024, 4096, 1024};
  const int Zs[6] = {16, 16, 16, 1, 1, 1};
  int base = 0;
  for (int j = 0; j < 6; ++j) {
    tab.src[j] = srcs[j];
    tab.dst[j] = dsts[j];
    tab.R[j] = Rs[j];
    tab.C[j] = Cs[j];
    tab.ntx[j] = Cs[j] / 32;
    tab.nty[j] = Rs[j] / 32;
    tab.base[j] = base;
    base += (Cs[j] / 32) * (Rs[j] / 32) * Zs[j];
  }
  tab.base[6] = base;  // 12288
  tr6_kernel<<<base, blk, 0, stream>>>(tab);

  ln_kernel<<<4096, blk, 0, stream>>>(x, ln1g, ln1b, sh8);              // xn
  gemm256<EPI_QKV><<<dim3(12, 16), dim3(512), 0, stream>>>(
      sh8, QKVT, 1024, nullptr, qb);
  trb_kernel<<<dim3(2, 64, 32), blk, 0, stream>>>(vb, vtb, 2048, 64);
  attn_kernel<<<dim3(16, 32), dim3(512), 0, stream>>>(qb, kb, vtb, sh8);
  gemm_bt<EPI_O, false><<<dim3(8, 32), blk, 0, stream>>>(
      sh8, WoT, 1024, bo, x, nullptr, hid);
  ln_kernel<<<4096, blk, 0, stream>>>(hid, ln2g, ln2b, sh8);            // hn
  gemm256<EPI_FF1><<<dim3(16, 16), dim3(512), 0, stream>>>(
      sh8, W1T, 1024, b1, h1);
  gemm_bt<EPI_FF2, true><<<dim3(16, 32), blk, 0, stream>>>(
      h1, W2T, 4096, b2, hid, nullptr, (float*)d_out);

  (void)in_sizes; (void)n_in; (void)out_size; (void)ws_size;
}